// Round 1
// baseline (794.486 us; speedup 1.0000x reference)
//
#include <hip/hip_runtime.h>
#include <math.h>

#define NNODES 100000
#define NEDGES 1600000
#define D 64

// ---------------- CSR build ----------------

__global__ void deg_kernel(const int* __restrict__ src, const int* __restrict__ dst,
                           int* __restrict__ deg_out, int* __restrict__ deg_in, int E) {
    int e = blockIdx.x * blockDim.x + threadIdx.x;
    if (e < E) {
        atomicAdd(&deg_out[src[e]], 1);
        atomicAdd(&deg_in[dst[e]], 1);
    }
}

__global__ void norm_kernel(const int* __restrict__ deg_out, const int* __restrict__ deg_in,
                            float* __restrict__ nsrc, float* __restrict__ ndst, int n) {
    int i = blockIdx.x * blockDim.x + threadIdx.x;
    if (i < n) {
        nsrc[i] = 1.0f / sqrtf(fmaxf((float)deg_out[i], 1.0f));
        ndst[i] = 1.0f / sqrtf(fmaxf((float)deg_in[i], 1.0f));
    }
}

// single-block exclusive scan of deg_in[0..n) -> row_ptr[0..n], row_ptr[n] = total
__global__ __launch_bounds__(1024) void scan_kernel(const int* __restrict__ deg,
                                                    int* __restrict__ row_ptr, int n) {
    __shared__ int part[1024];
    int t = threadIdx.x;
    int CH = (n + 1023) >> 10;           // chunk per thread
    int beg = t * CH;
    int end = min(beg + CH, n);
    int s = 0;
    for (int i = beg; i < end; ++i) s += deg[i];
    part[t] = s;
    __syncthreads();
    // Hillis-Steele inclusive scan over 1024 partials
    for (int o = 1; o < 1024; o <<= 1) {
        int v = (t >= o) ? part[t - o] : 0;
        __syncthreads();
        part[t] += v;
        __syncthreads();
    }
    int run = part[t] - s;               // exclusive prefix for this chunk
    for (int i = beg; i < end; ++i) { row_ptr[i] = run; run += deg[i]; }
    if (t == 1023) row_ptr[n] = part[1023];
}

__global__ void bucket_kernel(const int* __restrict__ src, const int* __restrict__ dst,
                              const int* __restrict__ row_ptr, int* __restrict__ cursor,
                              int* __restrict__ esrc, int E) {
    int e = blockIdx.x * blockDim.x + threadIdx.x;
    if (e < E) {
        int d = dst[e];
        int pos = row_ptr[d] + atomicAdd(&cursor[d], 1);
        esrc[pos] = src[e];
    }
}

// ---------------- fused GCN layer ----------------
// one wave per node; lane = feature index.
// FIRST=1: input = x, gather applies nsrc[s] per edge; epilogue = relu(h)*nsrc[node]
// FIRST=0: input = y2 (already pre-scaled); epilogue = plain h
template<int FIRST>
__global__ __launch_bounds__(256) void layer_kernel(const float* __restrict__ xin,
                                                    const int* __restrict__ row_ptr,
                                                    const int* __restrict__ esrc,
                                                    const float* __restrict__ nsrc,
                                                    const float* __restrict__ ndst,
                                                    const float* __restrict__ W,
                                                    const float* __restrict__ b,
                                                    float* __restrict__ out) {
    __shared__ float Wlds[D * D];
    __shared__ float blds[D];
    for (int i = threadIdx.x; i < D * D; i += 256) Wlds[i] = W[i];
    if (threadIdx.x < D) blds[threadIdx.x] = b[threadIdx.x];
    __syncthreads();

    int node = (blockIdx.x * blockDim.x + threadIdx.x) >> 6;   // N % 4 == 0, no partial waves
    int lane = threadIdx.x & 63;
    if (node >= NNODES) return;

    int beg = row_ptr[node];
    int end = row_ptr[node + 1];

    float acc0 = 0.0f, acc1 = 0.0f;
    int i = beg;
    for (; i + 2 <= end; i += 2) {
        int s0 = esrc[i];
        int s1 = esrc[i + 1];
        float v0 = xin[(size_t)s0 * D + lane];
        float v1 = xin[(size_t)s1 * D + lane];
        if (FIRST) { v0 *= nsrc[s0]; v1 *= nsrc[s1]; }
        acc0 += v0;
        acc1 += v1;
    }
    if (i < end) {
        int s = esrc[i];
        float v = xin[(size_t)s * D + lane];
        if (FIRST) v *= nsrc[s];
        acc0 += v;
    }

    float m = (acc0 + acc1) * ndst[node];

    // h[lane] = sum_k m[k] * W[k][lane] + b[lane], via wave broadcast
    float h = blds[lane];
#pragma unroll
    for (int k = 0; k < D; ++k) {
        float mk = __shfl(m, k, 64);
        h += mk * Wlds[k * D + lane];
    }

    if (FIRST) h = fmaxf(h, 0.0f) * nsrc[node];
    out[(size_t)node * D + lane] = h;
}

// ---------------- launcher ----------------

extern "C" void kernel_launch(void* const* d_in, const int* in_sizes, int n_in,
                              void* d_out, int out_size, void* d_ws, size_t ws_size,
                              hipStream_t stream) {
    const float* x  = (const float*)d_in[0];
    const int* src  = (const int*)d_in[1];
    const int* dst  = (const int*)d_in[2];
    const float* W1 = (const float*)d_in[3];
    const float* b1 = (const float*)d_in[4];
    const float* W2 = (const float*)d_in[5];
    const float* b2 = (const float*)d_in[6];
    float* out = (float*)d_out;

    // workspace bump allocator (256B aligned)
    size_t off = 0;
    auto alloc = [&](size_t bytes) -> void* {
        void* p = (char*)d_ws + off;
        off += (bytes + 255) & ~(size_t)255;
        return p;
    };
    int* deg_out   = (int*)alloc((size_t)NNODES * 4);
    int* deg_in    = (int*)alloc((size_t)NNODES * 4);
    int* row_ptr   = (int*)alloc((size_t)(NNODES + 1) * 4);
    int* cursor    = (int*)alloc((size_t)NNODES * 4);
    int* esrc      = (int*)alloc((size_t)NEDGES * 4);
    float* nsrc    = (float*)alloc((size_t)NNODES * 4);
    float* ndst    = (float*)alloc((size_t)NNODES * 4);
    float* y2      = (float*)alloc((size_t)NNODES * D * 4);
    (void)ws_size;

    hipMemsetAsync(deg_out, 0, (size_t)NNODES * 4, stream);
    hipMemsetAsync(deg_in,  0, (size_t)NNODES * 4, stream);
    hipMemsetAsync(cursor,  0, (size_t)NNODES * 4, stream);

    const int TB = 256;
    deg_kernel<<<(NEDGES + TB - 1) / TB, TB, 0, stream>>>(src, dst, deg_out, deg_in, NEDGES);
    norm_kernel<<<(NNODES + TB - 1) / TB, TB, 0, stream>>>(deg_out, deg_in, nsrc, ndst, NNODES);
    scan_kernel<<<1, 1024, 0, stream>>>(deg_in, row_ptr, NNODES);
    bucket_kernel<<<(NEDGES + TB - 1) / TB, TB, 0, stream>>>(src, dst, row_ptr, cursor, esrc, NEDGES);

    // 4 waves (nodes) per 256-thread block
    int layer_blocks = NNODES / 4;
    layer_kernel<1><<<layer_blocks, TB, 0, stream>>>(x,  row_ptr, esrc, nsrc, ndst, W1, b1, y2);
    layer_kernel<0><<<layer_blocks, TB, 0, stream>>>(y2, row_ptr, esrc, nsrc, ndst, W2, b2, out);
}

// Round 2
// 539.182 us; speedup vs baseline: 1.4735x; 1.4735x over previous
//
#include <hip/hip_runtime.h>
#include <math.h>

#define NNODES 100000
#define NEDGES 1600000
#define D 64
#define SCAN_CHUNK 1024
#define SCAN_BLOCKS ((NNODES + SCAN_CHUNK - 1) / SCAN_CHUNK)   // 98

// ---------------- degree count (int4-vectorized) ----------------
__global__ void deg_kernel(const int* __restrict__ src, const int* __restrict__ dst,
                           int* __restrict__ deg_out, int* __restrict__ deg_in) {
    int i = blockIdx.x * blockDim.x + threadIdx.x;
    if (i < NEDGES / 4) {
        int4 s4 = ((const int4*)src)[i];
        int4 d4 = ((const int4*)dst)[i];
        atomicAdd(&deg_out[s4.x], 1); atomicAdd(&deg_out[s4.y], 1);
        atomicAdd(&deg_out[s4.z], 1); atomicAdd(&deg_out[s4.w], 1);
        atomicAdd(&deg_in[d4.x], 1); atomicAdd(&deg_in[d4.y], 1);
        atomicAdd(&deg_in[d4.z], 1); atomicAdd(&deg_in[d4.w], 1);
    }
}

__global__ void norm_kernel(const int* __restrict__ deg_out, const int* __restrict__ deg_in,
                            float* __restrict__ nsrc, float* __restrict__ ndst) {
    int i = blockIdx.x * blockDim.x + threadIdx.x;
    if (i < NNODES) {
        nsrc[i] = 1.0f / sqrtf(fmaxf((float)deg_out[i], 1.0f));
        ndst[i] = 1.0f / sqrtf(fmaxf((float)deg_in[i], 1.0f));
    }
}

// ---------------- 3-phase exclusive scan of deg_in -> row_ptr (+cursor copy) ----------------
__global__ __launch_bounds__(256) void scan_reduce_kernel(const int* __restrict__ deg,
                                                          int* __restrict__ blocksum) {
    __shared__ int red[256];
    int b = blockIdx.x, t = threadIdx.x;
    int base = b * SCAN_CHUNK + t * 4;
    int s = 0;
    if (base + 4 <= NNODES) {
        int4 v = *(const int4*)(deg + base);
        s = v.x + v.y + v.z + v.w;
    } else {
        for (int j = 0; j < 4; ++j) if (base + j < NNODES) s += deg[base + j];
    }
    red[t] = s;
    __syncthreads();
    for (int o = 128; o > 0; o >>= 1) { if (t < o) red[t] += red[t + o]; __syncthreads(); }
    if (t == 0) blocksum[b] = red[0];
}

__global__ void scan_offsets_kernel(const int* __restrict__ blocksum,
                                    int* __restrict__ blockoff, int* __restrict__ row_ptr) {
    if (threadIdx.x == 0) {
        int run = 0;
        for (int b = 0; b < SCAN_BLOCKS; ++b) { blockoff[b] = run; run += blocksum[b]; }
        row_ptr[NNODES] = run;
    }
}

__global__ __launch_bounds__(256) void scan_final_kernel(const int* __restrict__ deg,
                                                         const int* __restrict__ blockoff,
                                                         int* __restrict__ row_ptr,
                                                         int* __restrict__ cursor) {
    __shared__ int wsum[4];
    int b = blockIdx.x, t = threadIdx.x;
    int lane = t & 63, w = t >> 6;
    int base = b * SCAN_CHUNK + t * 4;
    int v0 = 0, v1 = 0, v2 = 0, v3 = 0;
    if (base + 4 <= NNODES) {
        int4 v = *(const int4*)(deg + base);
        v0 = v.x; v1 = v.y; v2 = v.z; v3 = v.w;
    } else {
        if (base + 0 < NNODES) v0 = deg[base + 0];
        if (base + 1 < NNODES) v1 = deg[base + 1];
        if (base + 2 < NNODES) v2 = deg[base + 2];
        if (base + 3 < NNODES) v3 = deg[base + 3];
    }
    int tsum = v0 + v1 + v2 + v3;
    int incl = tsum;
    for (int o = 1; o < 64; o <<= 1) {
        int u = __shfl_up(incl, o, 64);
        if (lane >= o) incl += u;
    }
    int texcl = incl - tsum;
    if (lane == 63) wsum[w] = incl;
    __syncthreads();
    if (t == 0) {
        int run = 0;
        for (int i = 0; i < 4; ++i) { int x = wsum[i]; wsum[i] = run; run += x; }
    }
    __syncthreads();
    int p0 = blockoff[b] + wsum[w] + texcl;
    int p1 = p0 + v0, p2 = p1 + v1, p3 = p2 + v2;
    if (base + 0 < NNODES) { row_ptr[base + 0] = p0; cursor[base + 0] = p0; }
    if (base + 1 < NNODES) { row_ptr[base + 1] = p1; cursor[base + 1] = p1; }
    if (base + 2 < NNODES) { row_ptr[base + 2] = p2; cursor[base + 2] = p2; }
    if (base + 3 < NNODES) { row_ptr[base + 3] = p3; cursor[base + 3] = p3; }
}

__global__ void bucket_kernel(const int* __restrict__ src, const int* __restrict__ dst,
                              int* __restrict__ cursor, int* __restrict__ esrc) {
    int i = blockIdx.x * blockDim.x + threadIdx.x;
    if (i < NEDGES / 4) {
        int4 s4 = ((const int4*)src)[i];
        int4 d4 = ((const int4*)dst)[i];
        esrc[atomicAdd(&cursor[d4.x], 1)] = s4.x;
        esrc[atomicAdd(&cursor[d4.y], 1)] = s4.y;
        esrc[atomicAdd(&cursor[d4.z], 1)] = s4.z;
        esrc[atomicAdd(&cursor[d4.w], 1)] = s4.w;
    }
}

// ---------------- dense transform: out[v] = nsrc[v] * (xin[v] @ W) ----------------
// wave handles 4 nodes: lane = (g = sub-node [0..3], c = column-quad [0..15])
__global__ __launch_bounds__(256) void transform_kernel(const float* __restrict__ xin,
                                                        const float* __restrict__ W,
                                                        const float* __restrict__ nsrc,
                                                        float* __restrict__ out) {
    __shared__ float Wlds[D * D];
    for (int i = threadIdx.x; i < D * D; i += 256) Wlds[i] = W[i];
    __syncthreads();
    int wave = (blockIdx.x * 256 + threadIdx.x) >> 6;
    int lane = threadIdx.x & 63;
    int g = lane >> 4, c = lane & 15;
    int node0 = wave * 4;                       // NNODES % 4 == 0
    if (node0 >= NNODES) return;
    int node = node0 + g;
    float4 xv = *(const float4*)(xin + (size_t)node * D + (c << 2));
    float4 acc = {0.f, 0.f, 0.f, 0.f};
#pragma unroll
    for (int k = 0; k < D; ++k) {
        int srcl = (g << 4) | (k >> 2);
        float comp = ((k & 3) == 0) ? xv.x : ((k & 3) == 1) ? xv.y
                   : ((k & 3) == 2) ? xv.z : xv.w;
        float xk = __shfl(comp, srcl, 64);
        float4 w4 = *(const float4*)(Wlds + k * D + (c << 2));
        acc.x += xk * w4.x; acc.y += xk * w4.y;
        acc.z += xk * w4.z; acc.w += xk * w4.w;
    }
    float sc = nsrc[node];
    acc.x *= sc; acc.y *= sc; acc.z *= sc; acc.w *= sc;
    *(float4*)(out + (size_t)node * D + (c << 2)) = acc;
}

// ---------------- aggregation: out[v] = act(ndst[v]*sum_{e} t[src_e] + b) ----------------
// wave per node: lane = (g = edge-slot [0..3], c = column-quad [0..15]);
// one dwordx4 per lane gathers 4 edges' rows per instruction.
template<int RELU>
__global__ __launch_bounds__(256) void aggregate_kernel(const float* __restrict__ t,
                                                        const int* __restrict__ row_ptr,
                                                        const int* __restrict__ esrc,
                                                        const float* __restrict__ ndst,
                                                        const float* __restrict__ bias,
                                                        float* __restrict__ out) {
    int node = (blockIdx.x * 256 + threadIdx.x) >> 6;
    int lane = threadIdx.x & 63;
    int g = lane >> 4, c = lane & 15;
    if (node >= NNODES) return;
    int beg = row_ptr[node], end = row_ptr[node + 1];
    float4 a0 = {0.f, 0.f, 0.f, 0.f}, a1 = {0.f, 0.f, 0.f, 0.f};
    int i = beg;
    for (; i + 8 <= end; i += 8) {
        int s0 = esrc[i + g];
        int s1 = esrc[i + 4 + g];
        float4 v0 = *(const float4*)(t + (size_t)s0 * D + (c << 2));
        float4 v1 = *(const float4*)(t + (size_t)s1 * D + (c << 2));
        a0.x += v0.x; a0.y += v0.y; a0.z += v0.z; a0.w += v0.w;
        a1.x += v1.x; a1.y += v1.y; a1.z += v1.z; a1.w += v1.w;
    }
    for (; i < end; i += 4) {
        int e = i + g;
        if (e < end) {
            int s = esrc[e];
            float4 v = *(const float4*)(t + (size_t)s * D + (c << 2));
            a0.x += v.x; a0.y += v.y; a0.z += v.z; a0.w += v.w;
        }
    }
    a0.x += a1.x; a0.y += a1.y; a0.z += a1.z; a0.w += a1.w;
    // butterfly-reduce across the 4 edge-slot groups (lane bits 4,5)
    a0.x += __shfl_xor(a0.x, 16, 64); a0.y += __shfl_xor(a0.y, 16, 64);
    a0.z += __shfl_xor(a0.z, 16, 64); a0.w += __shfl_xor(a0.w, 16, 64);
    a0.x += __shfl_xor(a0.x, 32, 64); a0.y += __shfl_xor(a0.y, 32, 64);
    a0.z += __shfl_xor(a0.z, 32, 64); a0.w += __shfl_xor(a0.w, 32, 64);

    float nd = ndst[node];
    float4 b4 = *(const float4*)(bias + (c << 2));
    float4 h;
    h.x = a0.x * nd + b4.x; h.y = a0.y * nd + b4.y;
    h.z = a0.z * nd + b4.z; h.w = a0.w * nd + b4.w;
    if (RELU) {
        h.x = fmaxf(h.x, 0.f); h.y = fmaxf(h.y, 0.f);
        h.z = fmaxf(h.z, 0.f); h.w = fmaxf(h.w, 0.f);
    }
    if (g == 0) *(float4*)(out + (size_t)node * D + (c << 2)) = h;
}

// ---------------- launcher ----------------
extern "C" void kernel_launch(void* const* d_in, const int* in_sizes, int n_in,
                              void* d_out, int out_size, void* d_ws, size_t ws_size,
                              hipStream_t stream) {
    const float* x  = (const float*)d_in[0];
    const int* src  = (const int*)d_in[1];
    const int* dst  = (const int*)d_in[2];
    const float* W1 = (const float*)d_in[3];
    const float* b1 = (const float*)d_in[4];
    const float* W2 = (const float*)d_in[5];
    const float* b2 = (const float*)d_in[6];
    float* out = (float*)d_out;

    size_t off = 0;
    auto alloc = [&](size_t bytes) -> void* {
        void* p = (char*)d_ws + off;
        off += (bytes + 255) & ~(size_t)255;
        return p;
    };
    int* deg_out  = (int*)alloc((size_t)NNODES * 4);
    int* deg_in   = (int*)alloc((size_t)NNODES * 4);
    int* row_ptr  = (int*)alloc((size_t)(NNODES + 1) * 4);
    int* cursor   = (int*)alloc((size_t)NNODES * 4);
    int* esrc     = (int*)alloc((size_t)NEDGES * 4);
    float* nsrc   = (float*)alloc((size_t)NNODES * 4);
    float* ndst   = (float*)alloc((size_t)NNODES * 4);
    int* blocksum = (int*)alloc((size_t)SCAN_BLOCKS * 4);
    int* blockoff = (int*)alloc((size_t)SCAN_BLOCKS * 4);
    float* t_buf  = (float*)alloc((size_t)NNODES * D * 4);   // t1, later t2
    float* h1     = (float*)alloc((size_t)NNODES * D * 4);
    (void)ws_size;

    hipMemsetAsync(deg_out, 0, (size_t)NNODES * 4, stream);
    hipMemsetAsync(deg_in,  0, (size_t)NNODES * 4, stream);

    const int TB = 256;
    int eth = NEDGES / 4;                                   // 400000 threads
    deg_kernel<<<(eth + TB - 1) / TB, TB, 0, stream>>>(src, dst, deg_out, deg_in);
    norm_kernel<<<(NNODES + TB - 1) / TB, TB, 0, stream>>>(deg_out, deg_in, nsrc, ndst);
    scan_reduce_kernel<<<SCAN_BLOCKS, TB, 0, stream>>>(deg_in, blocksum);
    scan_offsets_kernel<<<1, 64, 0, stream>>>(blocksum, blockoff, row_ptr);
    scan_final_kernel<<<SCAN_BLOCKS, TB, 0, stream>>>(deg_in, blockoff, row_ptr, cursor);
    bucket_kernel<<<(eth + TB - 1) / TB, TB, 0, stream>>>(src, dst, cursor, esrc);

    int tf_blocks = NNODES / 16;                            // 4 nodes/wave, 4 waves/block
    int ag_blocks = NNODES / 4;                             // 1 node/wave, 4 waves/block
    transform_kernel<<<tf_blocks, TB, 0, stream>>>(x, W1, nsrc, t_buf);
    aggregate_kernel<1><<<ag_blocks, TB, 0, stream>>>(t_buf, row_ptr, esrc, ndst, b1, h1);
    transform_kernel<<<tf_blocks, TB, 0, stream>>>(h1, W2, nsrc, t_buf);
    aggregate_kernel<0><<<ag_blocks, TB, 0, stream>>>(t_buf, row_ptr, esrc, ndst, b2, out);
}

// Round 3
// 363.300 us; speedup vs baseline: 2.1869x; 1.4841x over previous
//
#include <hip/hip_runtime.h>
#include <math.h>

#define NN 100000
#define NE 1600000
#define D 64

#define HS 32                       // edge slices
#define SLICE (NE / HS)             // 50000 edges per slice (divisible by 4)
#define HC 7                        // hist node-chunks
#define HB 16000                    // bins per hist chunk (packed u16: 8000 words, 2*32KB LDS)
#define HW (HB / 2)
#define NW (NN / 2)                 // 50000 packed words per slice row
#define SC 7                        // scatter chunks
#define SB 15000                    // bins per scatter chunk (60KB LDS cursors)

#define SCAN_CHUNK 1024
#define SCAN_BLOCKS ((NN + SCAN_CHUNK - 1) / SCAN_CHUNK)   // 98

// ---------------- phase A: per-(chunk,slice) packed LDS histograms ----------------
__global__ __launch_bounds__(256) void hist_kernel(const int* __restrict__ src,
                                                   const int* __restrict__ dst,
                                                   unsigned* __restrict__ histO,
                                                   unsigned* __restrict__ histI) {
    __shared__ unsigned hO[HW];
    __shared__ unsigned hI[HW];
    int c = blockIdx.x / HS;
    int s = blockIdx.x % HS;
    int t = threadIdx.x;
    for (int w = t; w < HW; w += 256) { hO[w] = 0u; hI[w] = 0u; }
    __syncthreads();

    unsigned lo = (unsigned)(c * HB);
    unsigned span = min((unsigned)HB, (unsigned)NN - lo);
    const int4* s4 = (const int4*)(src + s * SLICE);
    const int4* d4 = (const int4*)(dst + s * SLICE);
    int nq = SLICE / 4;                                 // 12500
    for (int i = t; i < nq; i += 256) {
        int4 a = s4[i];
        int4 b = d4[i];
        unsigned r;
        r = (unsigned)a.x - lo; if (r < span) atomicAdd(&hO[r >> 1], 1u << ((r & 1) << 4));
        r = (unsigned)a.y - lo; if (r < span) atomicAdd(&hO[r >> 1], 1u << ((r & 1) << 4));
        r = (unsigned)a.z - lo; if (r < span) atomicAdd(&hO[r >> 1], 1u << ((r & 1) << 4));
        r = (unsigned)a.w - lo; if (r < span) atomicAdd(&hO[r >> 1], 1u << ((r & 1) << 4));
        r = (unsigned)b.x - lo; if (r < span) atomicAdd(&hI[r >> 1], 1u << ((r & 1) << 4));
        r = (unsigned)b.y - lo; if (r < span) atomicAdd(&hI[r >> 1], 1u << ((r & 1) << 4));
        r = (unsigned)b.z - lo; if (r < span) atomicAdd(&hI[r >> 1], 1u << ((r & 1) << 4));
        r = (unsigned)b.w - lo; if (r < span) atomicAdd(&hI[r >> 1], 1u << ((r & 1) << 4));
    }
    __syncthreads();
    int wlo = (int)(lo >> 1);
    int wspan = (int)(span >> 1);                       // spans are even
    for (int w = t; w < wspan; w += 256) {
        histO[(size_t)s * NW + wlo + w] = hO[w];
        histI[(size_t)s * NW + wlo + w] = hI[w];
    }
}

// ---------------- reduce partials -> deg_in, nsrc, ndst ----------------
__global__ __launch_bounds__(256) void reduce_norm_kernel(const unsigned* __restrict__ histO,
                                                          const unsigned* __restrict__ histI,
                                                          int* __restrict__ deg_in,
                                                          float* __restrict__ nsrc,
                                                          float* __restrict__ ndst) {
    int w = blockIdx.x * 256 + threadIdx.x;
    if (w >= NW) return;
    unsigned aO = 0u, aI = 0u;
    for (int s = 0; s < HS; ++s) {
        aO += histO[(size_t)s * NW + w];                // packed sums: totals < 65536
        aI += histI[(size_t)s * NW + w];
    }
    int n0 = w * 2, n1 = n0 + 1;
    float dO0 = (float)(aO & 0xFFFFu), dO1 = (float)(aO >> 16);
    float dI0 = (float)(aI & 0xFFFFu), dI1 = (float)(aI >> 16);
    nsrc[n0] = 1.0f / sqrtf(fmaxf(dO0, 1.0f));
    nsrc[n1] = 1.0f / sqrtf(fmaxf(dO1, 1.0f));
    ndst[n0] = 1.0f / sqrtf(fmaxf(dI0, 1.0f));
    ndst[n1] = 1.0f / sqrtf(fmaxf(dI1, 1.0f));
    deg_in[n0] = (int)(aI & 0xFFFFu);
    deg_in[n1] = (int)(aI >> 16);
}

// ---------------- 3-phase exclusive scan of deg_in -> row_ptr ----------------
__global__ __launch_bounds__(256) void scan_reduce_kernel(const int* __restrict__ deg,
                                                          int* __restrict__ blocksum) {
    __shared__ int red[256];
    int b = blockIdx.x, t = threadIdx.x;
    int base = b * SCAN_CHUNK + t * 4;
    int s = 0;
    if (base + 4 <= NN) {
        int4 v = *(const int4*)(deg + base);
        s = v.x + v.y + v.z + v.w;
    } else {
        for (int j = 0; j < 4; ++j) if (base + j < NN) s += deg[base + j];
    }
    red[t] = s;
    __syncthreads();
    for (int o = 128; o > 0; o >>= 1) { if (t < o) red[t] += red[t + o]; __syncthreads(); }
    if (t == 0) blocksum[b] = red[0];
}

__global__ void scan_offsets_kernel(const int* __restrict__ blocksum,
                                    int* __restrict__ blockoff, int* __restrict__ row_ptr) {
    if (threadIdx.x == 0) {
        int run = 0;
        for (int b = 0; b < SCAN_BLOCKS; ++b) { blockoff[b] = run; run += blocksum[b]; }
        row_ptr[NN] = run;
    }
}

__global__ __launch_bounds__(256) void scan_final_kernel(const int* __restrict__ deg,
                                                         const int* __restrict__ blockoff,
                                                         int* __restrict__ row_ptr) {
    __shared__ int wsum[4];
    int b = blockIdx.x, t = threadIdx.x;
    int lane = t & 63, w = t >> 6;
    int base = b * SCAN_CHUNK + t * 4;
    int v0 = 0, v1 = 0, v2 = 0, v3 = 0;
    if (base + 4 <= NN) {
        int4 v = *(const int4*)(deg + base);
        v0 = v.x; v1 = v.y; v2 = v.z; v3 = v.w;
    } else {
        if (base + 0 < NN) v0 = deg[base + 0];
        if (base + 1 < NN) v1 = deg[base + 1];
        if (base + 2 < NN) v2 = deg[base + 2];
        if (base + 3 < NN) v3 = deg[base + 3];
    }
    int tsum = v0 + v1 + v2 + v3;
    int incl = tsum;
    for (int o = 1; o < 64; o <<= 1) {
        int u = __shfl_up(incl, o, 64);
        if (lane >= o) incl += u;
    }
    int texcl = incl - tsum;
    if (lane == 63) wsum[w] = incl;
    __syncthreads();
    if (t == 0) {
        int run = 0;
        for (int i = 0; i < 4; ++i) { int x = wsum[i]; wsum[i] = run; run += x; }
    }
    __syncthreads();
    int p0 = blockoff[b] + wsum[w] + texcl;
    int p1 = p0 + v0, p2 = p1 + v1, p3 = p2 + v2;
    if (base + 0 < NN) row_ptr[base + 0] = p0;
    if (base + 1 < NN) row_ptr[base + 1] = p1;
    if (base + 2 < NN) row_ptr[base + 2] = p2;
    if (base + 3 < NN) row_ptr[base + 3] = p3;
}

// ---------------- per-(slice,bin) start offsets ----------------
__global__ __launch_bounds__(256) void offsets_kernel(const unsigned* __restrict__ histI,
                                                      const int* __restrict__ row_ptr,
                                                      int* __restrict__ offsets) {
    int b = blockIdx.x * 256 + threadIdx.x;
    if (b >= NN) return;
    int w = b >> 1, sh = (b & 1) << 4;
    int run = row_ptr[b];
    for (int s = 0; s < HS; ++s) {
        int cnt = (int)((histI[(size_t)s * NW + w] >> sh) & 0xFFFFu);
        offsets[(size_t)s * NN + b] = run;
        run += cnt;
    }
}

// ---------------- scatter edges into CSR buckets (LDS cursors only) ----------------
__global__ __launch_bounds__(256) void scatter_kernel(const int* __restrict__ src,
                                                      const int* __restrict__ dst,
                                                      const int* __restrict__ offsets,
                                                      int* __restrict__ esrc) {
    __shared__ int cur[SB];
    int c = blockIdx.x / HS;
    int s = blockIdx.x % HS;
    int t = threadIdx.x;
    unsigned lo = (unsigned)(c * SB);
    unsigned span = min((unsigned)SB, (unsigned)NN - lo);
    for (int b = t; b < (int)span; b += 256) cur[b] = offsets[(size_t)s * NN + lo + b];
    __syncthreads();

    const int4* s4 = (const int4*)(src + s * SLICE);
    const int4* d4 = (const int4*)(dst + s * SLICE);
    int nq = SLICE / 4;
    for (int i = t; i < nq; i += 256) {
        int4 a = s4[i];
        int4 b = d4[i];
        unsigned r;
        r = (unsigned)b.x - lo; if (r < span) esrc[atomicAdd(&cur[r], 1)] = a.x;
        r = (unsigned)b.y - lo; if (r < span) esrc[atomicAdd(&cur[r], 1)] = a.y;
        r = (unsigned)b.z - lo; if (r < span) esrc[atomicAdd(&cur[r], 1)] = a.z;
        r = (unsigned)b.w - lo; if (r < span) esrc[atomicAdd(&cur[r], 1)] = a.w;
    }
}

// ---------------- dense transform: out[v] = nsrc[v] * (xin[v] @ W) ----------------
__global__ __launch_bounds__(256) void transform_kernel(const float* __restrict__ xin,
                                                        const float* __restrict__ W,
                                                        const float* __restrict__ nsrc,
                                                        float* __restrict__ out) {
    __shared__ float Wlds[D * D];
    for (int i = threadIdx.x; i < D * D; i += 256) Wlds[i] = W[i];
    __syncthreads();
    int wave = (blockIdx.x * 256 + threadIdx.x) >> 6;
    int lane = threadIdx.x & 63;
    int g = lane >> 4, c = lane & 15;
    int node0 = wave * 4;
    if (node0 >= NN) return;
    int node = node0 + g;
    float4 xv = *(const float4*)(xin + (size_t)node * D + (c << 2));
    float4 acc = {0.f, 0.f, 0.f, 0.f};
#pragma unroll
    for (int k = 0; k < D; ++k) {
        int srcl = (g << 4) | (k >> 2);
        float comp = ((k & 3) == 0) ? xv.x : ((k & 3) == 1) ? xv.y
                   : ((k & 3) == 2) ? xv.z : xv.w;
        float xk = __shfl(comp, srcl, 64);
        float4 w4 = *(const float4*)(Wlds + k * D + (c << 2));
        acc.x += xk * w4.x; acc.y += xk * w4.y;
        acc.z += xk * w4.z; acc.w += xk * w4.w;
    }
    float sc = nsrc[node];
    acc.x *= sc; acc.y *= sc; acc.z *= sc; acc.w *= sc;
    *(float4*)(out + (size_t)node * D + (c << 2)) = acc;
}

// ---------------- aggregation ----------------
template<int RELU>
__global__ __launch_bounds__(256) void aggregate_kernel(const float* __restrict__ t,
                                                        const int* __restrict__ row_ptr,
                                                        const int* __restrict__ esrc,
                                                        const float* __restrict__ ndst,
                                                        const float* __restrict__ bias,
                                                        float* __restrict__ out) {
    int node = (blockIdx.x * 256 + threadIdx.x) >> 6;
    int lane = threadIdx.x & 63;
    int g = lane >> 4, c = lane & 15;
    if (node >= NN) return;
    int beg = row_ptr[node], end = row_ptr[node + 1];
    float4 a0 = {0.f, 0.f, 0.f, 0.f}, a1 = {0.f, 0.f, 0.f, 0.f};
    int i = beg;
    for (; i + 8 <= end; i += 8) {
        int s0 = esrc[i + g];
        int s1 = esrc[i + 4 + g];
        float4 v0 = *(const float4*)(t + (size_t)s0 * D + (c << 2));
        float4 v1 = *(const float4*)(t + (size_t)s1 * D + (c << 2));
        a0.x += v0.x; a0.y += v0.y; a0.z += v0.z; a0.w += v0.w;
        a1.x += v1.x; a1.y += v1.y; a1.z += v1.z; a1.w += v1.w;
    }
    for (; i < end; i += 4) {
        int e = i + g;
        if (e < end) {
            int s = esrc[e];
            float4 v = *(const float4*)(t + (size_t)s * D + (c << 2));
            a0.x += v.x; a0.y += v.y; a0.z += v.z; a0.w += v.w;
        }
    }
    a0.x += a1.x; a0.y += a1.y; a0.z += a1.z; a0.w += a1.w;
    a0.x += __shfl_xor(a0.x, 16, 64); a0.y += __shfl_xor(a0.y, 16, 64);
    a0.z += __shfl_xor(a0.z, 16, 64); a0.w += __shfl_xor(a0.w, 16, 64);
    a0.x += __shfl_xor(a0.x, 32, 64); a0.y += __shfl_xor(a0.y, 32, 64);
    a0.z += __shfl_xor(a0.z, 32, 64); a0.w += __shfl_xor(a0.w, 32, 64);

    float nd = ndst[node];
    float4 b4 = *(const float4*)(bias + (c << 2));
    float4 h;
    h.x = a0.x * nd + b4.x; h.y = a0.y * nd + b4.y;
    h.z = a0.z * nd + b4.z; h.w = a0.w * nd + b4.w;
    if (RELU) {
        h.x = fmaxf(h.x, 0.f); h.y = fmaxf(h.y, 0.f);
        h.z = fmaxf(h.z, 0.f); h.w = fmaxf(h.w, 0.f);
    }
    if (g == 0) *(float4*)(out + (size_t)node * D + (c << 2)) = h;
}

// ---------------- launcher ----------------
extern "C" void kernel_launch(void* const* d_in, const int* in_sizes, int n_in,
                              void* d_out, int out_size, void* d_ws, size_t ws_size,
                              hipStream_t stream) {
    const float* x  = (const float*)d_in[0];
    const int* src  = (const int*)d_in[1];
    const int* dst  = (const int*)d_in[2];
    const float* W1 = (const float*)d_in[3];
    const float* b1 = (const float*)d_in[4];
    const float* W2 = (const float*)d_in[5];
    const float* b2 = (const float*)d_in[6];
    float* out = (float*)d_out;

    size_t off = 0;
    auto alloc = [&](size_t bytes) -> void* {
        void* p = (char*)d_ws + off;
        off += (bytes + 255) & ~(size_t)255;
        return p;
    };
    int* deg_in   = (int*)alloc((size_t)NN * 4);
    int* row_ptr  = (int*)alloc((size_t)(NN + 1) * 4);
    float* nsrc   = (float*)alloc((size_t)NN * 4);
    float* ndst   = (float*)alloc((size_t)NN * 4);
    int* blocksum = (int*)alloc((size_t)SCAN_BLOCKS * 4);
    int* blockoff = (int*)alloc((size_t)SCAN_BLOCKS * 4);
    int* esrc     = (int*)alloc((size_t)NE * 4);                  // 6.4 MB
    float* t_buf  = (float*)alloc((size_t)NN * D * 4);            // 25.6 MB
    float* h1     = (float*)alloc((size_t)NN * D * 4);            // 25.6 MB
    (void)ws_size;

    // preprocessing scratch aliases t_buf (dead until transform1):
    // histO (6.4MB) | histI (6.4MB) | offsets (12.8MB) = 25.6MB exactly
    unsigned* histO = (unsigned*)t_buf;
    unsigned* histI = histO + (size_t)HS * NW;
    int* offsets    = (int*)(histI + (size_t)HS * NW);

    const int TB = 256;
    hist_kernel<<<HC * HS, TB, 0, stream>>>(src, dst, histO, histI);
    reduce_norm_kernel<<<(NW + TB - 1) / TB, TB, 0, stream>>>(histO, histI, deg_in, nsrc, ndst);
    scan_reduce_kernel<<<SCAN_BLOCKS, TB, 0, stream>>>(deg_in, blocksum);
    scan_offsets_kernel<<<1, 64, 0, stream>>>(blocksum, blockoff, row_ptr);
    scan_final_kernel<<<SCAN_BLOCKS, TB, 0, stream>>>(deg_in, blockoff, row_ptr);
    offsets_kernel<<<(NN + TB - 1) / TB, TB, 0, stream>>>(histI, row_ptr, offsets);
    scatter_kernel<<<SC * HS, TB, 0, stream>>>(src, dst, offsets, esrc);

    int tf_blocks = NN / 16;
    int ag_blocks = NN / 4;
    transform_kernel<<<tf_blocks, TB, 0, stream>>>(x, W1, nsrc, t_buf);
    aggregate_kernel<1><<<ag_blocks, TB, 0, stream>>>(t_buf, row_ptr, esrc, ndst, b1, h1);
    transform_kernel<<<tf_blocks, TB, 0, stream>>>(h1, W2, nsrc, t_buf);
    aggregate_kernel<0><<<ag_blocks, TB, 0, stream>>>(t_buf, row_ptr, esrc, ndst, b2, out);
}